// Round 5
// baseline (8325.131 us; speedup 1.0000x reference)
//
#include <hip/hip_runtime.h>
#include <stdint.h>

#define NSAMP 400
#define NC 512

#if __has_builtin(__builtin_amdgcn_exp2f)
#define EXP2F(x) __builtin_amdgcn_exp2f(x)
#else
#define EXP2F(x) __expf((x) * 0.6931471805599453f)
#endif
#if __has_builtin(__builtin_amdgcn_logf)
#define LOG2F(x) __builtin_amdgcn_logf(x)
#else
#define LOG2F(x) (__logf(x) * 1.4426950408889634f)
#endif

// ---------------------------------------------------------------------------
// Scalar (SALU) threefry for the wave-uniform per-sample key derivation.
// ---------------------------------------------------------------------------
static __device__ __forceinline__ uint32_t rotl32_s(uint32_t v, int n) {
  return (v << n) | (v >> (32 - n));
}
#define TFS(x0, x1, R) { x0 += x1; x1 = rotl32_s(x1, R); x1 ^= x0; }
static __device__ __forceinline__ void threefry2x32_s(
    uint32_t k0, uint32_t k1, uint32_t x0, uint32_t x1,
    uint32_t& o0, uint32_t& o1)
{
  const uint32_t ks2 = k0 ^ k1 ^ 0x1BD11BDAu;
  x0 += k0; x1 += k1;
  TFS(x0,x1,13) TFS(x0,x1,15) TFS(x0,x1,26) TFS(x0,x1, 6)
  x0 += k1; x1 += ks2 + 1u;
  TFS(x0,x1,17) TFS(x0,x1,29) TFS(x0,x1,16) TFS(x0,x1,24)
  x0 += ks2; x1 += k0 + 2u;
  TFS(x0,x1,13) TFS(x0,x1,15) TFS(x0,x1,26) TFS(x0,x1, 6)
  x0 += k0; x1 += k1 + 3u;
  TFS(x0,x1,17) TFS(x0,x1,29) TFS(x0,x1,16) TFS(x0,x1,24)
  x0 += k1; x1 += ks2 + 4u;
  TFS(x0,x1,13) TFS(x0,x1,15) TFS(x0,x1,26) TFS(x0,x1, 6)
  x0 += ks2; x1 += k0 + 5u;
  o0 = x0; o1 = x1;
}

// ---------------------------------------------------------------------------
// Inline-asm 8-wide interleaved threefry core. Pins the exact instruction
// stream: per round, 8 independent v_add_u32, 8 independent v_alignbit_b32
// (rot uses OLD x1 -> independent of the adds), then 8 v_xor_b32. Dependency
// distance = 8 insts (~16 issue cy) >> VALU latency, so a single wave runs at
// issue rate. This removes the compiler's liveness-minimizing serialization
// seen in R1-R4 (VGPR pinned 28-52, dur flat ~7.2ms).
// alignbit amount = 32 - R (funnel-shift-right == rotl).
// ---------------------------------------------------------------------------
#define ADD8 \
  "v_add_u32 %[a0],%[a0],%[b0]\n\t" "v_add_u32 %[a1],%[a1],%[b1]\n\t" \
  "v_add_u32 %[a2],%[a2],%[b2]\n\t" "v_add_u32 %[a3],%[a3],%[b3]\n\t" \
  "v_add_u32 %[a4],%[a4],%[b4]\n\t" "v_add_u32 %[a5],%[a5],%[b5]\n\t" \
  "v_add_u32 %[a6],%[a6],%[b6]\n\t" "v_add_u32 %[a7],%[a7],%[b7]\n\t"
#define ROT8(n) \
  "v_alignbit_b32 %[b0],%[b0],%[b0]," #n "\n\t" \
  "v_alignbit_b32 %[b1],%[b1],%[b1]," #n "\n\t" \
  "v_alignbit_b32 %[b2],%[b2],%[b2]," #n "\n\t" \
  "v_alignbit_b32 %[b3],%[b3],%[b3]," #n "\n\t" \
  "v_alignbit_b32 %[b4],%[b4],%[b4]," #n "\n\t" \
  "v_alignbit_b32 %[b5],%[b5],%[b5]," #n "\n\t" \
  "v_alignbit_b32 %[b6],%[b6],%[b6]," #n "\n\t" \
  "v_alignbit_b32 %[b7],%[b7],%[b7]," #n "\n\t"
#define XOR8 \
  "v_xor_b32 %[b0],%[b0],%[a0]\n\t" "v_xor_b32 %[b1],%[b1],%[a1]\n\t" \
  "v_xor_b32 %[b2],%[b2],%[a2]\n\t" "v_xor_b32 %[b3],%[b3],%[a3]\n\t" \
  "v_xor_b32 %[b4],%[b4],%[a4]\n\t" "v_xor_b32 %[b5],%[b5],%[a5]\n\t" \
  "v_xor_b32 %[b6],%[b6],%[a6]\n\t" "v_xor_b32 %[b7],%[b7],%[a7]\n\t"
#define RND(n) ADD8 ROT8(n) XOR8
#define INJ8(ka, kb) \
  "v_add_u32 %[a0]," ka ",%[a0]\n\t" "v_add_u32 %[a1]," ka ",%[a1]\n\t" \
  "v_add_u32 %[a2]," ka ",%[a2]\n\t" "v_add_u32 %[a3]," ka ",%[a3]\n\t" \
  "v_add_u32 %[a4]," ka ",%[a4]\n\t" "v_add_u32 %[a5]," ka ",%[a5]\n\t" \
  "v_add_u32 %[a6]," ka ",%[a6]\n\t" "v_add_u32 %[a7]," ka ",%[a7]\n\t" \
  "v_add_u32 %[b0]," kb ",%[b0]\n\t" "v_add_u32 %[b1]," kb ",%[b1]\n\t" \
  "v_add_u32 %[b2]," kb ",%[b2]\n\t" "v_add_u32 %[b3]," kb ",%[b3]\n\t" \
  "v_add_u32 %[b4]," kb ",%[b4]\n\t" "v_add_u32 %[b5]," kb ",%[b5]\n\t" \
  "v_add_u32 %[b6]," kb ",%[b6]\n\t" "v_add_u32 %[b7]," kb ",%[b7]\n\t"

// erfinv (Giles/XLA coefficients) on log2 basis fused with exp2:
// returns 2^(p(u)*u*sd2 + m2), sd2 = sd*sqrt2*log2e, m2 = m*log2e.
static __device__ __forceinline__ float softexp(float u, float L, float sd2, float m2) {
  float p;
  if (L > -7.2134752f) {                    // w = -ln2*L < 5 : central branch
    float w = fmaf(L, -0.69314718f, -2.5f);
    p =              2.81022636e-08f;
    p = fmaf(p, w,   3.43273939e-07f);
    p = fmaf(p, w,  -3.5233877e-06f);
    p = fmaf(p, w,  -4.39150654e-06f);
    p = fmaf(p, w,   0.00021858087f);
    p = fmaf(p, w,  -0.00125372503f);
    p = fmaf(p, w,  -0.00417768164f);
    p = fmaf(p, w,   0.246640727f);
    p = fmaf(p, w,   1.50140941f);
  } else {                                   // tail, ~0.34%/lane
    float w = __builtin_amdgcn_sqrtf(L * -0.69314718f) - 3.0f;
    p =             -0.000200214257f;
    p = fmaf(p, w,   0.000100950558f);
    p = fmaf(p, w,   0.00134934322f);
    p = fmaf(p, w,  -0.00367342844f);
    p = fmaf(p, w,   0.00573950773f);
    p = fmaf(p, w,  -0.0076224613f);
    p = fmaf(p, w,   0.00943887047f);
    p = fmaf(p, w,   1.00167406f);
    p = fmaf(p, w,   2.83297682f);
  }
  float px = p * u;
  return EXP2F(fmaf(px, sd2, m2));
}

__global__ __launch_bounds__(256)
void mc_softmax_kernel(const float* __restrict__ mean,
                       const float* __restrict__ var,
                       float* __restrict__ out)
{
  const int lane  = threadIdx.x & 63;
  const int row   = (blockIdx.x << 2) + (threadIdx.x >> 6);
  const int cbase = lane << 2;

  const float* mr = mean + (size_t)row * NC;
  const float* vr = var  + (size_t)row * NC;

  const float L2E = 1.4426950408889634f;   // log2(e)
  const float S2L = 2.0402788959f;         // sqrt(2)*log2(e)
  float4 t0 = *(const float4*)(mr + cbase);
  float4 t1 = *(const float4*)(mr + 256 + cbase);
  float4 v0 = *(const float4*)(vr + cbase);
  float4 v1 = *(const float4*)(vr + 256 + cbase);
  float m2_0 = t0.x*L2E, m2_1 = t0.y*L2E, m2_2 = t0.z*L2E, m2_3 = t0.w*L2E;
  float m2_4 = t1.x*L2E, m2_5 = t1.y*L2E, m2_6 = t1.z*L2E, m2_7 = t1.w*L2E;
  float sd_0 = __builtin_amdgcn_sqrtf(v0.x)*S2L, sd_1 = __builtin_amdgcn_sqrtf(v0.y)*S2L;
  float sd_2 = __builtin_amdgcn_sqrtf(v0.z)*S2L, sd_3 = __builtin_amdgcn_sqrtf(v0.w)*S2L;
  float sd_4 = __builtin_amdgcn_sqrtf(v1.x)*S2L, sd_5 = __builtin_amdgcn_sqrtf(v1.y)*S2L;
  float sd_6 = __builtin_amdgcn_sqrtf(v1.z)*S2L, sd_7 = __builtin_amdgcn_sqrtf(v1.w)*S2L;

  float ac0=0.f, ac1=0.f, ac2=0.f, ac3=0.f, ac4=0.f, ac5=0.f, ac6=0.f, ac7=0.f;

  const uint32_t base = (uint32_t)(row * NC + cbase);
  const uint32_t c0 = base + 0u,   c1 = base + 1u,   c2 = base + 2u,   c3 = base + 3u;
  const uint32_t c4 = base + 256u, c5 = base + 257u, c6 = base + 258u, c7 = base + 259u;
  const float lo = -0.99999994f;   // nextafter(-1, 0) in f32

  for (int s = 0; s < NSAMP; ++s) {
    // key_s = threefry((0,42),(0,s)) — uniform; readfirstlane pins SGPRs.
    uint32_t k0r, k1r;
    threefry2x32_s(0u, 42u, 0u, (uint32_t)s, k0r, k1r);
    const uint32_t k0  = __builtin_amdgcn_readfirstlane(k0r);
    const uint32_t k1  = __builtin_amdgcn_readfirstlane(k1r);
    const uint32_t ks2 = k0 ^ k1 ^ 0x1BD11BDAu;
    const uint32_t i1 = ks2 + 1u, i2 = k0 + 2u, i3 = k1 + 3u,
                   i4 = ks2 + 4u, i5 = k0 + 5u;

    // Initial key injection (x0=0+k0, x1=cnt+k1) done in C.
    uint32_t a0 = k0, a1 = k0, a2 = k0, a3 = k0, a4 = k0, a5 = k0, a6 = k0, a7 = k0;
    uint32_t b0 = c0 + k1, b1 = c1 + k1, b2 = c2 + k1, b3 = c3 + k1;
    uint32_t b4 = c4 + k1, b5 = c5 + k1, b6 = c6 + k1, b7 = c7 + k1;

    asm(
      RND(19) RND(17) RND(6) RND(26)          // R = 13,15,26,6
      INJ8("%[k1]", "%[i1]")
      RND(15) RND(3) RND(16) RND(8)           // R = 17,29,16,24
      INJ8("%[ks2]", "%[i2]")
      RND(19) RND(17) RND(6) RND(26)
      INJ8("%[k0]", "%[i3]")
      RND(15) RND(3) RND(16) RND(8)
      INJ8("%[k1]", "%[i4]")
      RND(19) RND(17) RND(6) RND(26)
      INJ8("%[ks2]", "%[i5]")
      : [a0]"+v"(a0), [a1]"+v"(a1), [a2]"+v"(a2), [a3]"+v"(a3),
        [a4]"+v"(a4), [a5]"+v"(a5), [a6]"+v"(a6), [a7]"+v"(a7),
        [b0]"+v"(b0), [b1]"+v"(b1), [b2]"+v"(b2), [b3]"+v"(b3),
        [b4]"+v"(b4), [b5]"+v"(b5), [b6]"+v"(b6), [b7]"+v"(b7)
      : [k0]"s"(k0), [k1]"s"(k1), [ks2]"s"(ks2),
        [i1]"s"(i1), [i2]"s"(i2), [i3]"s"(i3), [i4]"s"(i4), [i5]"s"(i5)
    );

    // u and L per element (branch-free), then branchy poly+exp.
    float u_0,u_1,u_2,u_3,u_4,u_5,u_6,u_7, L_0,L_1,L_2,L_3,L_4,L_5,L_6,L_7;
#define P1(j) { \
    uint32_t bits = a##j ^ b##j; \
    float f = __uint_as_float(__builtin_amdgcn_alignbit(0x7Fu, bits, 9u)) - 1.0f; \
    float u = fmaf(f, 2.0f, lo); \
    u_##j = u; L_##j = LOG2F(fmaf(u, -u, 1.0f)); }
    P1(0) P1(1) P1(2) P1(3) P1(4) P1(5) P1(6) P1(7)
#undef P1

    float e0 = softexp(u_0, L_0, sd_0, m2_0);
    float e1 = softexp(u_1, L_1, sd_1, m2_1);
    float e2 = softexp(u_2, L_2, sd_2, m2_2);
    float e3 = softexp(u_3, L_3, sd_3, m2_3);
    float e4 = softexp(u_4, L_4, sd_4, m2_4);
    float e5 = softexp(u_5, L_5, sd_5, m2_5);
    float e6 = softexp(u_6, L_6, sd_6, m2_6);
    float e7 = softexp(u_7, L_7, sd_7, m2_7);

    float sum = ((e0 + e1) + (e2 + e3)) + ((e4 + e5) + (e6 + e7));
#pragma unroll
    for (int off = 32; off >= 1; off >>= 1)
      sum += __shfl_xor(sum, off);
    const float inv = __builtin_amdgcn_rcpf(sum);

    ac0 = fmaf(e0, inv, ac0); ac1 = fmaf(e1, inv, ac1);
    ac2 = fmaf(e2, inv, ac2); ac3 = fmaf(e3, inv, ac3);
    ac4 = fmaf(e4, inv, ac4); ac5 = fmaf(e5, inv, ac5);
    ac6 = fmaf(e6, inv, ac6); ac7 = fmaf(e7, inv, ac7);
  }

  float* orow = out + (size_t)row * NC;
  const float sc = 1.0f / (float)NSAMP;
  float4 o0, o1;
  o0.x = ac0*sc; o0.y = ac1*sc; o0.z = ac2*sc; o0.w = ac3*sc;
  o1.x = ac4*sc; o1.y = ac5*sc; o1.z = ac6*sc; o1.w = ac7*sc;
  *(float4*)(orow + cbase)       = o0;
  *(float4*)(orow + 256 + cbase) = o1;
}

extern "C" void kernel_launch(void* const* d_in, const int* in_sizes, int n_in,
                              void* d_out, int out_size, void* d_ws, size_t ws_size,
                              hipStream_t stream) {
  const float* mean = (const float*)d_in[0];
  const float* var  = (const float*)d_in[1];
  float* out        = (float*)d_out;

  const int rows = out_size / NC;        // 16384
  const int blocks = rows / 4;           // 4 rows (waves) per 256-thread block
  mc_softmax_kernel<<<blocks, 256, 0, stream>>>(mean, var, out);
}

// Round 6
// 6504.260 us; speedup vs baseline: 1.2800x; 1.2800x over previous
//
#include <hip/hip_runtime.h>
#include <stdint.h>

#define NSAMP 400
#define NC 512

#if __has_builtin(__builtin_amdgcn_exp2f)
#define EXP2F(x) __builtin_amdgcn_exp2f(x)
#else
#define EXP2F(x) __expf((x) * 0.6931471805599453f)
#endif
#if __has_builtin(__builtin_amdgcn_logf)
#define LOG2F(x) __builtin_amdgcn_logf(x)
#else
#define LOG2F(x) (__logf(x) * 1.4426950408889634f)
#endif

static __device__ __forceinline__ uint32_t rotl32(uint32_t v, int n) {
  return (v << n) | (v >> (32 - n));
}

// Full threefry2x32 (used once per sample in the LDS-table setup loop).
#define TFS(x0, x1, R) { x0 += x1; x1 = rotl32(x1, R); x1 ^= x0; }
static __device__ __forceinline__ void threefry2x32_full(
    uint32_t k0, uint32_t k1, uint32_t x0, uint32_t x1,
    uint32_t& o0, uint32_t& o1)
{
  const uint32_t ks2 = k0 ^ k1 ^ 0x1BD11BDAu;
  x0 += k0; x1 += k1;
  TFS(x0,x1,13) TFS(x0,x1,15) TFS(x0,x1,26) TFS(x0,x1, 6)
  x0 += k1; x1 += ks2 + 1u;
  TFS(x0,x1,17) TFS(x0,x1,29) TFS(x0,x1,16) TFS(x0,x1,24)
  x0 += ks2; x1 += k0 + 2u;
  TFS(x0,x1,13) TFS(x0,x1,15) TFS(x0,x1,26) TFS(x0,x1, 6)
  x0 += k0; x1 += k1 + 3u;
  TFS(x0,x1,17) TFS(x0,x1,29) TFS(x0,x1,16) TFS(x0,x1,24)
  x0 += k1; x1 += ks2 + 4u;
  TFS(x0,x1,13) TFS(x0,x1,15) TFS(x0,x1,26) TFS(x0,x1, 6)
  x0 += ks2; x1 += k0 + 5u;
  o0 = x0; o1 = x1;
}

// ---------------------------------------------------------------------------
// Op-minimized per-element threefry (bit-identical to the full cipher):
//  - round-1 add folded into init:       x0 = (cnt + k1) + k0
//  - injections 1-4 fused with the next round's add: x0 = x0 + x1 + ka
//    -> single v_add3_u32 instead of two v_add_u32.  (-5 int ops/element)
// Per-sample constants (k0,k1,ks2, ks2+1, k0+2, k1+3, ks2+4, k0+5) come from
// an LDS table (two broadcast ds_read_b128), not recomputed per sample.
// ---------------------------------------------------------------------------
#define R3OP(R)          { x0 += x1; x1 = rotl32(x1, R) ^ x0; }
#define INJR(ka, kb, R)  { x1 += kb; x0 = x0 + x1 + ka; x1 = rotl32(x1, R) ^ x0; }

static __device__ __forceinline__ uint32_t tf_bits_fused(
    uint32_t k0, uint32_t k1, uint32_t ks2,
    uint32_t I1, uint32_t I2, uint32_t I3, uint32_t I4, uint32_t I5,
    uint32_t cnt)
{
  uint32_t x1 = cnt + k1;
  uint32_t x0 = x1 + k0;              // == x0_init(k0) + x1  (round-1 add)
  x1 = rotl32(x1, 13) ^ x0;           // round 1 tail
  R3OP(15) R3OP(26) R3OP(6)
  INJR(k1,  I1, 17) R3OP(29) R3OP(16) R3OP(24)
  INJR(ks2, I2, 13) R3OP(15) R3OP(26) R3OP(6)
  INJR(k0,  I3, 17) R3OP(29) R3OP(16) R3OP(24)
  INJR(k1,  I4, 13) R3OP(15) R3OP(26) R3OP(6)
  x0 += ks2; x1 += I5;                // final injection
  return x0 ^ x1;                     // JAX partitionable 32-bit fold
}

// erfinv (Giles/XLA coefficients) on log2 basis fused with exp2:
// returns 2^(p(u)*u*sd2 + m2), sd2 = sd*sqrt2*log2e, m2 = m*log2e.
static __device__ __forceinline__ float softexp(float u, float L, float sd2, float m2) {
  float p;
  if (L > -7.2134752f) {                    // w = -ln2*L < 5 : central branch
    float w = fmaf(L, -0.69314718f, -2.5f);
    p =              2.81022636e-08f;
    p = fmaf(p, w,   3.43273939e-07f);
    p = fmaf(p, w,  -3.5233877e-06f);
    p = fmaf(p, w,  -4.39150654e-06f);
    p = fmaf(p, w,   0.00021858087f);
    p = fmaf(p, w,  -0.00125372503f);
    p = fmaf(p, w,  -0.00417768164f);
    p = fmaf(p, w,   0.246640727f);
    p = fmaf(p, w,   1.50140941f);
  } else {                                   // tail, ~0.34%/lane
    float w = __builtin_amdgcn_sqrtf(L * -0.69314718f) - 3.0f;
    p =             -0.000200214257f;
    p = fmaf(p, w,   0.000100950558f);
    p = fmaf(p, w,   0.00134934322f);
    p = fmaf(p, w,  -0.00367342844f);
    p = fmaf(p, w,   0.00573950773f);
    p = fmaf(p, w,  -0.0076224613f);
    p = fmaf(p, w,   0.00943887047f);
    p = fmaf(p, w,   1.00167406f);
    p = fmaf(p, w,   2.83297682f);
  }
  float px = p * u;
  return EXP2F(fmaf(px, sd2, m2));
}

// One wave per row; 8 columns per lane; 4 waves/block.
__global__ __launch_bounds__(256)
void mc_softmax_kernel(const float* __restrict__ mean,
                       const float* __restrict__ var,
                       float* __restrict__ out)
{
  // Per-sample constant table: [s] = {k0, k1, ks2, ks2+1, k0+2, k1+3, ks2+4, k0+5}
  __shared__ __align__(16) uint32_t kc[NSAMP][8];
  for (int s = threadIdx.x; s < NSAMP; s += 256) {
    uint32_t a, b;
    threefry2x32_full(0u, 42u, 0u, (uint32_t)s, a, b);
    uint32_t ks2 = a ^ b ^ 0x1BD11BDAu;
    kc[s][0] = a;        kc[s][1] = b;
    kc[s][2] = ks2;      kc[s][3] = ks2 + 1u;
    kc[s][4] = a + 2u;   kc[s][5] = b + 3u;
    kc[s][6] = ks2 + 4u; kc[s][7] = a + 5u;
  }
  __syncthreads();

  const int lane  = threadIdx.x & 63;
  const int row   = (blockIdx.x << 2) + (threadIdx.x >> 6);
  const int cbase = lane << 2;

  const float* mr = mean + (size_t)row * NC;
  const float* vr = var  + (size_t)row * NC;

  float m2[8], sd2[8], acc[8];
  {
    const float L2E = 1.4426950408889634f;   // log2(e)
    const float S2L = 2.0402788959f;         // sqrt(2)*log2(e)
    float4 t0 = *(const float4*)(mr + cbase);
    float4 t1 = *(const float4*)(mr + 256 + cbase);
    m2[0] = t0.x * L2E; m2[1] = t0.y * L2E; m2[2] = t0.z * L2E; m2[3] = t0.w * L2E;
    m2[4] = t1.x * L2E; m2[5] = t1.y * L2E; m2[6] = t1.z * L2E; m2[7] = t1.w * L2E;
    float4 v0 = *(const float4*)(vr + cbase);
    float4 v1 = *(const float4*)(vr + 256 + cbase);
    sd2[0] = __builtin_amdgcn_sqrtf(v0.x) * S2L;
    sd2[1] = __builtin_amdgcn_sqrtf(v0.y) * S2L;
    sd2[2] = __builtin_amdgcn_sqrtf(v0.z) * S2L;
    sd2[3] = __builtin_amdgcn_sqrtf(v0.w) * S2L;
    sd2[4] = __builtin_amdgcn_sqrtf(v1.x) * S2L;
    sd2[5] = __builtin_amdgcn_sqrtf(v1.y) * S2L;
    sd2[6] = __builtin_amdgcn_sqrtf(v1.z) * S2L;
    sd2[7] = __builtin_amdgcn_sqrtf(v1.w) * S2L;
  }
#pragma unroll
  for (int j = 0; j < 8; ++j) acc[j] = 0.0f;

  const uint32_t base = (uint32_t)(row * NC + cbase);
  const float lo = -0.99999994f;   // nextafter(-1, 0) in f32

  for (int s = 0; s < NSAMP; ++s) {
    const uint4 ca = *(const uint4*)&kc[s][0];   // broadcast ds_read_b128
    const uint4 cb = *(const uint4*)&kc[s][4];
    const uint32_t k0 = ca.x, k1 = ca.y, ks2 = ca.z, I1 = ca.w;
    const uint32_t I2 = cb.x, I3 = cb.y, I4 = cb.z, I5 = cb.w;

    // Phase 1: 8 independent fused threefry -> u -> log chains, branch-free.
    float u8[8], L8[8];
#pragma unroll
    for (int j = 0; j < 8; ++j) {
      const uint32_t cnt = base + (uint32_t)(j < 4 ? j : 252 + j);
      uint32_t bits = tf_bits_fused(k0, k1, ks2, I1, I2, I3, I4, I5, cnt);
      // (bits>>9)|0x3f800000 in one alignbit: ({0x7F:bits} >> 9)
      float f = __uint_as_float(__builtin_amdgcn_alignbit(0x7Fu, bits, 9u)) - 1.0f;
      float u = fmaf(f, 2.0f, lo);           // max(lo,.) provably identity
      u8[j] = u;
      L8[j] = LOG2F(fmaf(u, -u, 1.0f));
    }

    // Phase 2: branchy erfinv-poly + exp2.
    float e8[8], sum = 0.0f;
#pragma unroll
    for (int j = 0; j < 8; ++j) {
      e8[j] = softexp(u8[j], L8[j], sd2[j], m2[j]);
      sum += e8[j];
    }

    // Phase 3: wave-wide denominator.
#pragma unroll
    for (int off = 32; off >= 1; off >>= 1)
      sum += __shfl_xor(sum, off);
    const float inv = __builtin_amdgcn_rcpf(sum);
#pragma unroll
    for (int j = 0; j < 8; ++j)
      acc[j] = fmaf(e8[j], inv, acc[j]);
  }

  float* orow = out + (size_t)row * NC;
  const float sc = 1.0f / (float)NSAMP;
  float4 o0, o1;
  o0.x = acc[0] * sc; o0.y = acc[1] * sc; o0.z = acc[2] * sc; o0.w = acc[3] * sc;
  o1.x = acc[4] * sc; o1.y = acc[5] * sc; o1.z = acc[6] * sc; o1.w = acc[7] * sc;
  *(float4*)(orow + cbase)       = o0;
  *(float4*)(orow + 256 + cbase) = o1;
}

extern "C" void kernel_launch(void* const* d_in, const int* in_sizes, int n_in,
                              void* d_out, int out_size, void* d_ws, size_t ws_size,
                              hipStream_t stream) {
  const float* mean = (const float*)d_in[0];
  const float* var  = (const float*)d_in[1];
  float* out        = (float*)d_out;

  const int rows = out_size / NC;        // 16384
  const int blocks = rows / 4;           // 4 rows (waves) per 256-thread block
  mc_softmax_kernel<<<blocks, 256, 0, stream>>>(mean, var, out);
}